// Round 1
// baseline (214.492 us; speedup 1.0000x reference)
//
#include <hip/hip_runtime.h>

// qkv: (4, 8192, 3, 16, 64) f32 ; out: (4, 8192, 16, 64) f32
constexpr int   Bn    = 4;
constexpr int   Nn    = 8192;
constexpr int   Hn    = 16;
constexpr int   Dn    = 64;
constexpr int   QKV_N = 3 * Hn * Dn;                   // 3072
constexpr long long QKV_B = (long long)Nn * QKV_N;     // 25165824
constexpr int   OUT_N = Hn * Dn;                       // 1024
constexpr long long OUT_B = (long long)Nn * OUT_N;     // 8388608

// Kernel 1: fused 3-branch dilated attention producing UNNORMALIZED out,
// plus double-precision column sums (sum over n) via atomics.
// Work unit (b,h,j): group positions {j, j+2048, j+4096, j+6144}.
// One wave handles 4 consecutive j (sub = lane>>4), d split in quads (t16 = lane&15).
__global__ __launch_bounds__(256) void dil_main(const float* __restrict__ qkv,
                                                float* __restrict__ out,
                                                double* __restrict__ colsum) {
  const int tid = threadIdx.x;
  const int w   = tid >> 6;        // wave in block (0..3)
  const int l   = tid & 63;
  const int sub = l >> 4;          // which j within the wave's group of 4
  const int t16 = l & 15;          // which d-quad (d = t16*4 .. t16*4+3)
  const int bh  = blockIdx.y;      // 0..63
  const int b   = bh >> 4;
  const int h   = bh & 15;

  const size_t qbase = (size_t)b * QKV_B + (size_t)h * Dn + (size_t)t16 * 4;
  const size_t obase = (size_t)b * OUT_B + (size_t)h * Dn + (size_t)t16 * 4;

  double cs0 = 0.0, cs1 = 0.0, cs2 = 0.0, cs3 = 0.0;

  for (int it = 0; it < 8; ++it) {
    const int g = blockIdx.x * 32 + w * 8 + it;   // j-group 0..511
    const int j = g * 4 + sub;                    // 0..2047

    float q[4][4], k[4][4], v[4][4];
#pragma unroll
    for (int m = 0; m < 4; ++m) {
      const size_t o = qbase + (size_t)(m * 2048 + j) * QKV_N;
      float4 t;
      t = *(const float4*)(qkv + o);
      q[m][0] = t.x; q[m][1] = t.y; q[m][2] = t.z; q[m][3] = t.w;
      t = *(const float4*)(qkv + o + 1024);
      k[m][0] = t.x; k[m][1] = t.y; k[m][2] = t.z; k[m][3] = t.w;
      t = *(const float4*)(qkv + o + 2048);
      v[m][0] = t.x; v[m][1] = t.y; v[m][2] = t.z; v[m][3] = t.w;
    }

    // 4x4 score matrix, partial over this lane's d-quad
    float S[4][4];
#pragma unroll
    for (int m = 0; m < 4; ++m)
#pragma unroll
      for (int m2 = 0; m2 < 4; ++m2)
        S[m][m2] = q[m][0] * k[m2][0] + q[m][1] * k[m2][1] +
                   q[m][2] * k[m2][2] + q[m][3] * k[m2][3];

    // butterfly-reduce across the 16 lanes of this sub-group
#pragma unroll
    for (int off = 1; off < 16; off <<= 1) {
#pragma unroll
      for (int m = 0; m < 4; ++m)
#pragma unroll
        for (int m2 = 0; m2 < 4; ++m2)
          S[m][m2] += __shfl_xor(S[m][m2], off, 64);
    }

#pragma unroll
    for (int m = 0; m < 4; ++m)
#pragma unroll
      for (int m2 = 0; m2 < 4; ++m2)
        S[m][m2] *= 0.125f;   // 1/sqrt(64)

    float acc[4][4];

    // ---- branch 1 (r=1): softmax over all 4 keys, every position ----
#pragma unroll
    for (int m = 0; m < 4; ++m) {
      float mx = fmaxf(fmaxf(S[m][0], S[m][1]), fmaxf(S[m][2], S[m][3]));
      float e0 = __expf(S[m][0] - mx);
      float e1 = __expf(S[m][1] - mx);
      float e2 = __expf(S[m][2] - mx);
      float e3 = __expf(S[m][3] - mx);
      float inv = 1.0f / (e0 + e1 + e2 + e3);
      e0 *= inv; e1 *= inv; e2 *= inv; e3 *= inv;
#pragma unroll
      for (int c = 0; c < 4; ++c)
        acc[m][c] = e0 * v[0][c] + e1 * v[1][c] + e2 * v[2][c] + e3 * v[3][c];
    }

    // ---- branch 2 (r=2): applies iff j even  <=>  sub even ----
    if ((sub & 1) == 0) {
#pragma unroll
      for (int m = 0; m < 4; ++m) {
        const int a  = m & 1;
        const int b2 = a + 2;
        float sa = S[m][a], sb = S[m][b2];
        float mx = fmaxf(sa, sb);
        float ea = __expf(sa - mx);
        float eb = __expf(sb - mx);
        float inv = 1.0f / (ea + eb);
        ea *= inv; eb *= inv;
#pragma unroll
        for (int c = 0; c < 4; ++c)
          acc[m][c] += ea * v[a][c] + eb * v[b2][c];
      }
    }

    // ---- branch 3 (r=4): applies iff j % 4 == 0  <=>  sub == 0 ----
    if (sub == 0) {
#pragma unroll
      for (int m = 0; m < 4; ++m)
#pragma unroll
        for (int c = 0; c < 4; ++c)
          acc[m][c] += v[m][c];
    }

    // ---- store unnormalized out, accumulate column sums ----
#pragma unroll
    for (int m = 0; m < 4; ++m) {
      float4 st = make_float4(acc[m][0], acc[m][1], acc[m][2], acc[m][3]);
      *(float4*)(out + obase + (size_t)(m * 2048 + j) * OUT_N) = st;
      cs0 += (double)acc[m][0];
      cs1 += (double)acc[m][1];
      cs2 += (double)acc[m][2];
      cs3 += (double)acc[m][3];
    }
  }

  double* cp = colsum + (size_t)bh * Dn + (size_t)t16 * 4;
  atomicAdd(cp + 0, cs0);
  atomicAdd(cp + 1, cs1);
  atomicAdd(cp + 2, cs2);
  atomicAdd(cp + 3, cs3);
}

// Kernel 2: reciprocal table (4096 entries)
__global__ __launch_bounds__(256) void dil_recip(const double* __restrict__ colsum,
                                                 float* __restrict__ recip) {
  const int i = blockIdx.x * 256 + threadIdx.x;
  if (i < Bn * Hn * Dn)
    recip[i] = (float)(1.0 / colsum[i]);
}

// Kernel 3: out *= recip (broadcast over n)
__global__ __launch_bounds__(256) void dil_scale(float* __restrict__ out,
                                                 const float* __restrict__ recip) {
  const long long f = (long long)blockIdx.x * 256 + threadIdx.x;  // float4 index
  const int d4 = (int)(f & 15);
  const int h  = (int)((f >> 4) & 15);
  const int b  = (int)(f >> 21);
  const float4 r = ((const float4*)recip)[(b * 16 + h) * 16 + d4];
  float4 o = ((const float4*)out)[f];
  o.x *= r.x; o.y *= r.y; o.z *= r.z; o.w *= r.w;
  ((float4*)out)[f] = o;
}

extern "C" void kernel_launch(void* const* d_in, const int* in_sizes, int n_in,
                              void* d_out, int out_size, void* d_ws, size_t ws_size,
                              hipStream_t stream) {
  const float* qkv = (const float*)d_in[0];
  float* out = (float*)d_out;

  double* colsum = (double*)d_ws;                        // 4096 doubles = 32 KB
  float*  recip  = (float*)((char*)d_ws + 32768);        // 4096 floats  = 16 KB

  hipMemsetAsync(d_ws, 0, 4096 * sizeof(double), stream);

  dim3 grid1(16, 64);   // x: j-chunks, y: (b,h)
  dil_main<<<grid1, 256, 0, stream>>>(qkv, out, colsum);

  dil_recip<<<16, 256, 0, stream>>>(colsum, recip);

  const long long nf4 = (long long)Bn * Nn * Hn * Dn / 4;   // 8388608
  dil_scale<<<(int)(nf4 / 256), 256, 0, stream>>>(out, recip);
}